// Round 1
// baseline (2156.798 us; speedup 1.0000x reference)
//
#include <hip/hip_runtime.h>
#include <math.h>

#define BATCH 128
#define CIN 3
#define H 224
#define W 224
#define C1 16
#define H1 112
#define W1 112
#define HP 56
#define WP 56
#define C2 32
#define H2 28
#define W2 28

// ---------------------------------------------------------------------------
// Kernel 1: conv1 (stride2, pad1) -> per-channel sum / sumsq (no store).
// Grid: B*C1*H1*W1 / 256 = 100352 blocks. plane=12544 divisible by 256, so
// every block lives in a single (n,c) plane -> one atomicAdd pair per block.
// ---------------------------------------------------------------------------
__global__ __launch_bounds__(256) void conv1_stats_k(
    const float* __restrict__ x, const float* __restrict__ w1,
    const float* __restrict__ b1, float* __restrict__ s_sum,
    float* __restrict__ s_sq)
{
    __shared__ float wsm[27];
    __shared__ float red[256];
    __shared__ float red2[256];
    const int tid = threadIdx.x;
    const long long idx = (long long)blockIdx.x * 256 + tid;
    const int plane = H1 * W1;                 // 12544
    const int nc = (int)(idx / plane);
    const int p  = (int)(idx % plane);
    const int c = nc % C1;
    const int n = nc / C1;
    if (tid < 27) wsm[tid] = w1[c * 27 + tid];
    __syncthreads();
    const int oh = p / W1, ow = p % W1;
    float acc = b1[c];
#pragma unroll
    for (int i = 0; i < CIN; ++i) {
        const float* xp = x + ((long long)(n * CIN + i)) * (H * W);
#pragma unroll
        for (int kh = 0; kh < 3; ++kh) {
            const int ih = 2 * oh - 1 + kh;
            const bool rv = (ih >= 0) && (ih < H);
#pragma unroll
            for (int kw = 0; kw < 3; ++kw) {
                const int iw = 2 * ow - 1 + kw;
                const float v = (rv && iw >= 0 && iw < W) ? xp[ih * W + iw] : 0.0f;
                acc += wsm[i * 9 + kh * 3 + kw] * v;
            }
        }
    }
    red[tid]  = acc;
    red2[tid] = acc * acc;
    __syncthreads();
#pragma unroll
    for (int s = 128; s > 0; s >>= 1) {
        if (tid < s) { red[tid] += red[tid + s]; red2[tid] += red2[tid + s]; }
        __syncthreads();
    }
    if (tid == 0) {
        atomicAdd(&s_sum[c], red[0]);
        atomicAdd(&s_sq[c],  red2[0]);
    }
}

// ---------------------------------------------------------------------------
// BN finalize: scale = g*rsqrt(var+eps); shift = beta - mean*scale
// ---------------------------------------------------------------------------
__global__ void finalize_bn_k(const float* __restrict__ s_sum,
                              const float* __restrict__ s_sq,
                              const float* __restrict__ g,
                              const float* __restrict__ beta,
                              float* __restrict__ sc, int C, float invcount)
{
    int c = threadIdx.x;
    if (c < C) {
        float mean = s_sum[c] * invcount;
        float var  = s_sq[c] * invcount - mean * mean;
        float inv  = rsqrtf(var + 1e-5f);
        float scale = g[c] * inv;
        sc[c]     = scale;
        sc[C + c] = beta[c] - mean * scale;
    }
}

// ---------------------------------------------------------------------------
// Kernel 3: recompute conv1 fused with BN + ReLU + 2x2 maxpool.
// One thread per pooled output (B*C1*HP*WP = 6422528; /256 = 25088 blocks).
// The 2x2 conv-output window shares a 5x5 input patch per in-channel.
// ---------------------------------------------------------------------------
__global__ __launch_bounds__(256) void conv1_pool_k(
    const float* __restrict__ x, const float* __restrict__ w1,
    const float* __restrict__ b1, const float* __restrict__ sc,
    float* __restrict__ h1)
{
    __shared__ float wsm[C1 * 27];   // all conv1 weights (432 floats)
    __shared__ float scs[2 * C1];
    const int tid = threadIdx.x;
    for (int t = tid; t < C1 * 27; t += 256) wsm[t] = w1[t];
    if (tid < 2 * C1) scs[tid] = sc[tid];
    __syncthreads();
    const int idx = blockIdx.x * 256 + tid;
    const int plane = HP * WP;            // 3136
    const int p  = idx % plane;
    const int nc = idx / plane;
    const int c = nc % C1;
    const int n = nc / C1;
    const int ohp = p / WP, owp = p % WP;
    const float* wc = &wsm[c * 27];
    const float bb = b1[c];
    float a00 = bb, a01 = bb, a10 = bb, a11 = bb;
#pragma unroll
    for (int i = 0; i < CIN; ++i) {
        const float* xp = x + ((long long)(n * CIN + i)) * (H * W);
#pragma unroll
        for (int r = 0; r < 5; ++r) {
            const int ih = 4 * ohp - 1 + r;
            const bool rv = (ih >= 0) && (ih < H);
#pragma unroll
            for (int s = 0; s < 5; ++s) {
                const int iw = 4 * owp - 1 + s;
                const float v = (rv && iw >= 0 && iw < W) ? xp[ih * W + iw] : 0.0f;
                // conv output (dy,dx) uses tap (kh,kw) with r=2*dy+kh, s=2*dx+kw
                if (r < 3) {
                    if (s < 3)  a00 += wc[i * 9 + r * 3 + s] * v;
                    if (s >= 2) a01 += wc[i * 9 + r * 3 + (s - 2)] * v;
                }
                if (r >= 2) {
                    const int kh = r - 2;
                    if (s < 3)  a10 += wc[i * 9 + kh * 3 + s] * v;
                    if (s >= 2) a11 += wc[i * 9 + kh * 3 + (s - 2)] * v;
                }
            }
        }
    }
    const float scale = scs[c], shift = scs[C1 + c];
    float f00 = scale * a00 + shift;
    float f01 = scale * a01 + shift;
    float f10 = scale * a10 + shift;
    float f11 = scale * a11 + shift;
    float m = fmaxf(fmaxf(f00, f01), fmaxf(f10, f11));
    h1[idx] = fmaxf(m, 0.0f);   // relu(max) == max(relu) since relu monotone
}

// ---------------------------------------------------------------------------
// Kernel 4: conv2 (stride2, pad1) -> store y2 + per-channel stats.
// One block per (n, c2): 4096 blocks, 784 outputs each.
// ---------------------------------------------------------------------------
__global__ __launch_bounds__(256) void conv2_stats_k(
    const float* __restrict__ h1, const float* __restrict__ w2,
    const float* __restrict__ b2, float* __restrict__ y2,
    float* __restrict__ s_sum, float* __restrict__ s_sq)
{
    __shared__ float wsm[C1 * 9];     // 144 floats: this channel's filters
    __shared__ float red[256];
    __shared__ float red2[256];
    const int tid = threadIdx.x;
    const int n = blockIdx.x / C2;
    const int c = blockIdx.x % C2;
    for (int t = tid; t < C1 * 9; t += 256) wsm[t] = w2[c * (C1 * 9) + t];
    __syncthreads();
    const float bb = b2[c];
    float lsum = 0.0f, lsq = 0.0f;
    for (int p = tid; p < H2 * W2; p += 256) {
        const int oh = p / W2, ow = p % W2;
        float acc = bb;
#pragma unroll
        for (int i = 0; i < C1; ++i) {
            const float* hp = h1 + ((long long)(n * C1 + i)) * (HP * WP);
#pragma unroll
            for (int kh = 0; kh < 3; ++kh) {
                const int ih = 2 * oh - 1 + kh;
                const bool rv = (ih >= 0) && (ih < HP);
#pragma unroll
                for (int kw = 0; kw < 3; ++kw) {
                    const int iw = 2 * ow - 1 + kw;
                    const float v = (rv && iw >= 0 && iw < WP) ? hp[ih * WP + iw] : 0.0f;
                    acc += wsm[i * 9 + kh * 3 + kw] * v;
                }
            }
        }
        y2[(long long)blockIdx.x * (H2 * W2) + p] = acc;
        lsum += acc;
        lsq  += acc * acc;
    }
    red[tid] = lsum; red2[tid] = lsq;
    __syncthreads();
#pragma unroll
    for (int s = 128; s > 0; s >>= 1) {
        if (tid < s) { red[tid] += red[tid + s]; red2[tid] += red2[tid + s]; }
        __syncthreads();
    }
    if (tid == 0) {
        atomicAdd(&s_sum[c], red[0]);
        atomicAdd(&s_sq[c],  red2[0]);
    }
}

// ---------------------------------------------------------------------------
// Kernel 6: BN2 + ReLU + global avg pool + FC + cos head.
// One block per image; wave w handles channels w*8..w*8+7.
// ---------------------------------------------------------------------------
__global__ __launch_bounds__(256) void final_head_k(
    const float* __restrict__ y2, const float* __restrict__ sc2,
    const float* __restrict__ fcw, const float* __restrict__ fcb,
    float* __restrict__ out)
{
    __shared__ float feat[C2];
    const int n = blockIdx.x;
    const int tid = threadIdx.x;
    const int wave = tid >> 6, lane = tid & 63;
#pragma unroll
    for (int k = 0; k < 8; ++k) {
        const int c = wave * 8 + k;
        const float scale = sc2[c], shift = sc2[C2 + c];
        const float* yp = y2 + ((long long)(n * C2 + c)) * (H2 * W2);
        float s = 0.0f;
        for (int p = lane; p < H2 * W2; p += 64) {
            s += fmaxf(scale * yp[p] + shift, 0.0f);
        }
#pragma unroll
        for (int off = 32; off > 0; off >>= 1) s += __shfl_down(s, off);
        if (lane == 0) feat[c] = s * (1.0f / (H2 * W2));
    }
    __syncthreads();
    if (tid == 0) {
        float logit = fcb[0];
#pragma unroll
        for (int c = 0; c < C2; ++c) logit += feat[c] * fcw[c];
        float pc = cosf(logit);
        out[n * 2 + 0] = pc;
        out[n * 2 + 1] = 1.0f - pc;
    }
}

extern "C" void kernel_launch(void* const* d_in, const int* in_sizes, int n_in,
                              void* d_out, int out_size, void* d_ws, size_t ws_size,
                              hipStream_t stream) {
    const float* x   = (const float*)d_in[0];
    const float* w1  = (const float*)d_in[1];
    const float* b1  = (const float*)d_in[2];
    const float* g1  = (const float*)d_in[3];
    const float* be1 = (const float*)d_in[4];
    const float* w2  = (const float*)d_in[5];
    const float* b2  = (const float*)d_in[6];
    const float* g2  = (const float*)d_in[7];
    const float* be2 = (const float*)d_in[8];
    const float* fcw = (const float*)d_in[9];
    const float* fcb = (const float*)d_in[10];
    float* out = (float*)d_out;

    float* ws = (float*)d_ws;
    float* h1 = ws;                                        // 6,422,528 floats
    float* y2 = h1 + (size_t)BATCH * C1 * HP * WP;         // 3,211,264 floats
    float* stats = y2 + (size_t)BATCH * C2 * H2 * W2;      // 96 floats
    float* s1sum = stats;
    float* s1sq  = stats + 16;
    float* s2sum = stats + 32;
    float* s2sq  = stats + 64;
    float* sc1 = stats + 96;                               // 32 floats
    float* sc2 = sc1 + 32;                                 // 64 floats
    // total ws use: (6422528 + 3211264 + 96 + 32 + 64)*4 B ~= 38.5 MB

    hipMemsetAsync(stats, 0, 96 * sizeof(float), stream);

    conv1_stats_k<<<(BATCH * C1 * H1 * W1) / 256, 256, 0, stream>>>(x, w1, b1, s1sum, s1sq);
    finalize_bn_k<<<1, 64, 0, stream>>>(s1sum, s1sq, g1, be1, sc1, C1,
                                        1.0f / (float)(BATCH * H1 * W1));
    conv1_pool_k<<<(BATCH * C1 * HP * WP) / 256, 256, 0, stream>>>(x, w1, b1, sc1, h1);
    conv2_stats_k<<<BATCH * C2, 256, 0, stream>>>(h1, w2, b2, y2, s2sum, s2sq);
    finalize_bn_k<<<1, 64, 0, stream>>>(s2sum, s2sq, g2, be2, sc2, C2,
                                        1.0f / (float)(BATCH * H2 * W2));
    final_head_k<<<BATCH, 256, 0, stream>>>(y2, sc2, fcw, fcb, out);
}

// Round 2
// 383.246 us; speedup vs baseline: 5.6277x; 5.6277x over previous
//
#include <hip/hip_runtime.h>
#include <math.h>

#define BATCH 128
#define CIN 3
#define H 224
#define W 224
#define C1 16
#define H1 112
#define W1 112
#define HP 56
#define WP 56
#define C2 32
#define H2 28
#define W2 28

// ---------------------------------------------------------------------------
// Kernel 1: conv1 (s2,p1) + per-channel stats + 2x2 maxpool max/min, fused.
// Grid (14, 128): blockIdx.x = row-tile (4 pooled rows), blockIdx.y = image.
// LDS tile: x[3][17 rows][228] (input rows 16*ty-1 .. 16*ty+15, cols -1..224).
// Thread = one pooled position (224 active of 256), all 16 channels.
// Stores raw-conv window max and min per (c, pooled pos); BN applied later.
// ---------------------------------------------------------------------------
__global__ __launch_bounds__(256) void conv1_fused_k(
    const float* __restrict__ x, const float* __restrict__ w1,
    const float* __restrict__ b1,
    float* __restrict__ mx, float* __restrict__ mn,
    float* __restrict__ s_sum, float* __restrict__ s_sq)
{
    __shared__ float xs[3 * 17 * 228];
    __shared__ float red[4][8];
    __shared__ float red2[4][8];
    const int tid = threadIdx.x;
    const int ty  = blockIdx.x;          // 0..13
    const int n   = blockIdx.y;          // 0..127
    const int r0  = 16 * ty - 1;         // global input row of LDS row 0

    // ---- stage input tile: coalesced, unconditional streaming ----
#pragma unroll 4
    for (int e = tid; e < 3 * 17 * 228; e += 256) {
        const int col = e % 228;         // xs col; input col = col-1
        const int rl  = e / 228;
        const int ci  = rl / 17;
        const int l   = rl % 17;
        const int g   = r0 + l;
        const int gc  = col - 1;
        float v = 0.0f;
        if (g >= 0 && g < H && gc >= 0 && gc < W)
            v = x[((n * CIN + ci) * H + g) * W + gc];
        xs[e] = v;
    }
    __syncthreads();

    const bool active = tid < 224;
    const int pr  = active ? (tid / 56) : 0;   // local pooled row 0..3
    const int owp = active ? (tid % 56) : 0;   // pooled col 0..55

    // ---- compute: 2 halves of 8 output channels ----
#pragma unroll 1
    for (int h = 0; h < 2; ++h) {
        float acc[8][4];
#pragma unroll
        for (int j = 0; j < 8; ++j) {
            const float bb = b1[8 * h + j];          // uniform -> SGPR
            acc[j][0] = bb; acc[j][1] = bb; acc[j][2] = bb; acc[j][3] = bb;
        }
#pragma unroll
        for (int ci = 0; ci < CIN; ++ci) {
            // 5x5 patch into registers (b128 + b32 per row, conflict-light)
            float p_[5][5];
#pragma unroll
            for (int r = 0; r < 5; ++r) {
                const float* rowp = &xs[(ci * 17 + 4 * pr + r) * 228 + 4 * owp];
                const float4 t = *(const float4*)rowp;   // 16B-aligned
                p_[r][0] = t.x; p_[r][1] = t.y; p_[r][2] = t.z; p_[r][3] = t.w;
                p_[r][4] = rowp[4];
            }
#pragma unroll
            for (int j = 0; j < 8; ++j) {
                const float* wc = &w1[((8 * h + j) * CIN + ci) * 9]; // uniform -> s_load
#pragma unroll
                for (int kh = 0; kh < 3; ++kh) {
#pragma unroll
                    for (int kw = 0; kw < 3; ++kw) {
                        const float wv = wc[kh * 3 + kw];
                        acc[j][0] += wv * p_[kh][kw];
                        acc[j][1] += wv * p_[kh][kw + 2];
                        acc[j][2] += wv * p_[kh + 2][kw];
                        acc[j][3] += wv * p_[kh + 2][kw + 2];
                    }
                }
            }
        }
        // ---- per-channel: pooled max/min store + stats butterfly ----
#pragma unroll
        for (int j = 0; j < 8; ++j) {
            const float a0 = acc[j][0], a1 = acc[j][1], a2 = acc[j][2], a3 = acc[j][3];
            if (active) {
                const int c = 8 * h + j;
                const int o = (n * C1 + c) * (HP * WP) + (4 * ty + pr) * WP + owp;
                mx[o] = fmaxf(fmaxf(a0, a1), fmaxf(a2, a3));
                mn[o] = fminf(fminf(a0, a1), fminf(a2, a3));
            }
            float s  = active ? (a0 + a1 + a2 + a3) : 0.0f;
            float qq = active ? (a0 * a0 + a1 * a1 + a2 * a2 + a3 * a3) : 0.0f;
#pragma unroll
            for (int off = 32; off > 0; off >>= 1) {
                s  += __shfl_xor(s, off);
                qq += __shfl_xor(qq, off);
            }
            if ((tid & 63) == 0) { red[tid >> 6][j] = s; red2[tid >> 6][j] = qq; }
        }
        __syncthreads();
        if (tid < 8) {
            atomicAdd(&s_sum[8 * h + tid],
                      red[0][tid] + red[1][tid] + red[2][tid] + red[3][tid]);
            atomicAdd(&s_sq[8 * h + tid],
                      red2[0][tid] + red2[1][tid] + red2[2][tid] + red2[3][tid]);
        }
        __syncthreads();   // red reused next half
    }
}

// ---------------------------------------------------------------------------
// BN finalize: scale = g*rsqrt(var+eps); shift = beta - mean*scale
// ---------------------------------------------------------------------------
__global__ void finalize_bn_k(const float* __restrict__ s_sum,
                              const float* __restrict__ s_sq,
                              const float* __restrict__ g,
                              const float* __restrict__ beta,
                              float* __restrict__ sc, int C, float invcount)
{
    int c = threadIdx.x;
    if (c < C) {
        float mean = s_sum[c] * invcount;
        float var  = s_sq[c] * invcount - mean * mean;
        float scale = g[c] * rsqrtf(var + 1e-5f);
        sc[c]     = scale;
        sc[C + c] = beta[c] - mean * scale;
    }
}

// ---------------------------------------------------------------------------
// Kernel 2: conv2 (s2,p1) + stats; staging applies BN1+ReLU+pool-select:
//   h1 = max(0, max(scale*mx+shift, scale*mn+shift))   (covers both signs)
// Grid (4, 128): blockIdx.x = 7-output-row tile, blockIdx.y = image.
// LDS tile: h1[16][15 rows][60] (h1 rows 14*t-1..14*t+13, cols -1..56).
// Thread = one output position (196 active), acc over all 32 channels.
// ---------------------------------------------------------------------------
__global__ __launch_bounds__(256) void conv2_fused_k(
    const float* __restrict__ mx, const float* __restrict__ mn,
    const float* __restrict__ sc1, const float* __restrict__ w2,
    const float* __restrict__ b2, float* __restrict__ y2,
    float* __restrict__ s_sum, float* __restrict__ s_sq)
{
    __shared__ float hs[16 * 15 * 60];
    __shared__ float red[4][32];
    __shared__ float red2[4][32];
    const int tid = threadIdx.x;
    const int t4  = blockIdx.x;          // 0..3
    const int n   = blockIdx.y;
    const int r0  = 14 * t4 - 1;

    // ---- stage h1 tile (computed on the fly from mx/mn + BN1) ----
#pragma unroll 4
    for (int e = tid; e < 16 * 15 * 60; e += 256) {
        const int col = e % 60;          // h1 col = col-1
        const int rl  = e / 60;
        const int ci  = rl / 15;
        const int l   = rl % 15;
        const int g   = r0 + l;
        const int gc  = col - 1;
        float v = 0.0f;
        if (g >= 0 && g < HP && gc >= 0 && gc < WP) {
            const int o = (n * C1 + ci) * (HP * WP) + g * WP + gc;
            const float s = sc1[ci], t = sc1[C1 + ci];
            v = fmaxf(0.0f, fmaxf(s * mx[o] + t, s * mn[o] + t));
        }
        hs[e] = v;
    }
    __syncthreads();

    const bool active = tid < 196;
    const int ohl = active ? (tid / 28) : 0;  // local out row 0..6
    const int ow  = active ? (tid % 28) : 0;

    float acc[32];
#pragma unroll
    for (int c = 0; c < 32; ++c) acc[c] = b2[c];

#pragma unroll 1
    for (int ci = 0; ci < C1; ++ci) {
        float v[3][3];
#pragma unroll
        for (int kh = 0; kh < 3; ++kh)
#pragma unroll
            for (int kw = 0; kw < 3; ++kw)
                v[kh][kw] = hs[(ci * 15 + 2 * ohl + kh) * 60 + 2 * ow + kw];
#pragma unroll
        for (int c = 0; c < 32; ++c) {
            const float* wc = &w2[(c * C1 + ci) * 9];   // uniform -> s_load
            float a = acc[c];
            a += wc[0] * v[0][0]; a += wc[1] * v[0][1]; a += wc[2] * v[0][2];
            a += wc[3] * v[1][0]; a += wc[4] * v[1][1]; a += wc[5] * v[1][2];
            a += wc[6] * v[2][0]; a += wc[7] * v[2][1]; a += wc[8] * v[2][2];
            acc[c] = a;
        }
    }

    const int oh = 7 * t4 + ohl;
#pragma unroll
    for (int c = 0; c < 32; ++c) {
        const float a = acc[c];
        if (active) y2[(n * C2 + c) * (H2 * W2) + oh * W2 + ow] = a;
        float s  = active ? a : 0.0f;
        float qq = active ? a * a : 0.0f;
#pragma unroll
        for (int off = 32; off > 0; off >>= 1) {
            s  += __shfl_xor(s, off);
            qq += __shfl_xor(qq, off);
        }
        if ((tid & 63) == 0) { red[tid >> 6][c] = s; red2[tid >> 6][c] = qq; }
    }
    __syncthreads();
    if (tid < 32) {
        atomicAdd(&s_sum[tid], red[0][tid] + red[1][tid] + red[2][tid] + red[3][tid]);
    } else if (tid < 64) {
        const int c = tid - 32;
        atomicAdd(&s_sq[c], red2[0][c] + red2[1][c] + red2[2][c] + red2[3][c]);
    }
}

// ---------------------------------------------------------------------------
// Kernel 3: BN2 + ReLU + global avg pool + FC + cos head. Block per image.
// ---------------------------------------------------------------------------
__global__ __launch_bounds__(256) void final_head_k(
    const float* __restrict__ y2, const float* __restrict__ sc2,
    const float* __restrict__ fcw, const float* __restrict__ fcb,
    float* __restrict__ out)
{
    __shared__ float feat[C2];
    const int n = blockIdx.x;
    const int tid = threadIdx.x;
    const int wave = tid >> 6, lane = tid & 63;
#pragma unroll
    for (int k = 0; k < 8; ++k) {
        const int c = wave * 8 + k;
        const float scale = sc2[c], shift = sc2[C2 + c];
        const float* yp = y2 + (n * C2 + c) * (H2 * W2);
        float s = 0.0f;
        for (int p = lane; p < H2 * W2; p += 64)
            s += fmaxf(scale * yp[p] + shift, 0.0f);
#pragma unroll
        for (int off = 32; off > 0; off >>= 1) s += __shfl_down(s, off);
        if (lane == 0) feat[c] = s * (1.0f / (H2 * W2));
    }
    __syncthreads();
    if (tid == 0) {
        float logit = fcb[0];
#pragma unroll
        for (int c = 0; c < C2; ++c) logit += feat[c] * fcw[c];
        const float pc = cosf(logit);
        out[n * 2 + 0] = pc;
        out[n * 2 + 1] = 1.0f - pc;
    }
}

extern "C" void kernel_launch(void* const* d_in, const int* in_sizes, int n_in,
                              void* d_out, int out_size, void* d_ws, size_t ws_size,
                              hipStream_t stream) {
    const float* x   = (const float*)d_in[0];
    const float* w1  = (const float*)d_in[1];
    const float* b1  = (const float*)d_in[2];
    const float* g1  = (const float*)d_in[3];
    const float* be1 = (const float*)d_in[4];
    const float* w2  = (const float*)d_in[5];
    const float* b2  = (const float*)d_in[6];
    const float* g2  = (const float*)d_in[7];
    const float* be2 = (const float*)d_in[8];
    const float* fcw = (const float*)d_in[9];
    const float* fcb = (const float*)d_in[10];
    float* out = (float*)d_out;

    float* ws = (float*)d_ws;
    float* mx = ws;                                        // 6,422,528 floats
    float* mn = mx + (size_t)BATCH * C1 * HP * WP;         // 6,422,528
    float* y2 = mn + (size_t)BATCH * C1 * HP * WP;         // 3,211,264
    float* stats = y2 + (size_t)BATCH * C2 * H2 * W2;      // 96
    float* s1sum = stats;
    float* s1sq  = stats + 16;
    float* s2sum = stats + 32;
    float* s2sq  = stats + 64;
    float* sc1 = stats + 96;                               // 32
    float* sc2 = sc1 + 32;                                 // 64
    // ws use ~64.3 MB

    hipMemsetAsync(stats, 0, 96 * sizeof(float), stream);

    conv1_fused_k<<<dim3(14, BATCH), 256, 0, stream>>>(x, w1, b1, mx, mn, s1sum, s1sq);
    finalize_bn_k<<<1, 64, 0, stream>>>(s1sum, s1sq, g1, be1, sc1, C1,
                                        1.0f / (float)(BATCH * H1 * W1));
    conv2_fused_k<<<dim3(4, BATCH), 256, 0, stream>>>(mx, mn, sc1, w2, b2, y2, s2sum, s2sq);
    finalize_bn_k<<<1, 64, 0, stream>>>(s2sum, s2sq, g2, be2, sc2, C2,
                                        1.0f / (float)(BATCH * H2 * W2));
    final_head_k<<<BATCH, 256, 0, stream>>>(y2, sc2, fcw, fcb, out);
}